// Round 7
// baseline (188.135 us; speedup 1.0000x reference)
//
#include <hip/hip_runtime.h>
#include <math.h>

// Problem constants
constexpr int kT = 512;
constexpr int kB = 8;
constexpr int kD = 512;
constexpr int kM = 128;
constexpr int kNPairs = kT * kB;        // 4096 independent (t,b) pairs
constexpr int kGP = 8;                  // pairs per block (gates kernel)
constexpr int kGateThreads = 512;       // 8 waves: 4 matrices x 2 d-halves
constexpr int kThreads = 256;
constexpr int kRB = 64;                 // rows per stream block (2 blocks/pair)

typedef float f32x4 __attribute__((ext_vector_type(4)));
typedef float f32x2 __attribute__((ext_vector_type(2)));

// ---------------------------------------------------------------------------
// Kernel A: gates. 512 blocks x 512 threads (8 waves), 8 pairs/block.
// Wave w: matrix m = w&3, d-half dh = w>>2 (d in [dh*256, dh*256+256)).
// Lane l owns columns {2l, 2l+1}. Each weight float2 is loaded once and
// FMA'd against all 8 pairs. x[p][d] is wave-uniform -> scalar s_load.
// d-halves reduced via LDS. 512 MB total weight L2 traffic; 16 waves/CU.
// ---------------------------------------------------------------------------
__global__ __launch_bounds__(kGateThreads)
void mlstm_gates(const float* __restrict__ x,
                 const float* __restrict__ n_prev,
                 const float* __restrict__ Wq, const float* __restrict__ bq,
                 const float* __restrict__ Wk, const float* __restrict__ bk,
                 const float* __restrict__ Wv, const float* __restrict__ bv,
                 const float* __restrict__ wi, const float* __restrict__ bi,
                 const float* __restrict__ wf, const float* __restrict__ bf,
                 const float* __restrict__ Wo, const float* __restrict__ bo,
                 float* __restrict__ gq, float* __restrict__ gk,
                 float* __restrict__ gv, float* __restrict__ go,
                 float* __restrict__ gi, float* __restrict__ gf,
                 float* __restrict__ ginv,
                 float* __restrict__ out_n)
{
    __shared__ float sq[kGP][kM];          // q (for n-phase)
    __shared__ float sk[kGP][kM];          // k scaled by 1/sqrt(M)
    __shared__ float sacc[4][kGP][kM];     // 16 KB: dh=1 partial sums
    __shared__ float sif[kGP][2];          // i, f per pair

    const int tid = threadIdx.x;
    const int w   = tid >> 6;              // wave 0..7
    const int m   = w & 3;                 // matrix q,k,v,o
    const int dh  = w >> 2;                // d-half 0/1
    const int l   = tid & 63;              // lane
    const int pair_base = blockIdx.x * kGP;
    const float* __restrict__ xblk = x + (size_t)pair_base * kD;

    const float* __restrict__ Wm = (m == 0) ? Wq : (m == 1) ? Wk : (m == 2) ? Wv : Wo;
    const float* __restrict__ bm = (m == 0) ? bq : (m == 1) ? bk : (m == 2) ? bv : bo;

    const int c = 2 * l;                   // column base for this lane

    // ---------------- matvec: 4 matrices x 2 d-halves across 8 waves --------
    f32x2 acc[kGP];
    #pragma unroll
    for (int p = 0; p < kGP; ++p) acc[p] = (f32x2){0.f, 0.f};

    {
        const float* __restrict__ Wh = Wm + (size_t)(dh * (kD / 2)) * kM;
        const float* __restrict__ xh = xblk + dh * (kD / 2);
        #pragma unroll 4
        for (int d = 0; d < kD / 2; ++d) {
            const f32x2 w2 = *reinterpret_cast<const f32x2*>(Wh + d * kM + c);
            #pragma unroll
            for (int p = 0; p < kGP; ++p) {
                const float xv = xh[p * kD + d];        // wave-uniform -> s_load
                const f32x2 xx = {xv, xv};
                acc[p] += xx * w2;                       // v_pk_fma_f32
            }
        }
    }

    if (dh == 1) {
        #pragma unroll
        for (int p = 0; p < kGP; ++p)
            *reinterpret_cast<f32x2*>(&sacc[m][p][c]) = acc[p];
    }
    __syncthreads();

    if (dh == 0) {
        const f32x2 b2 = *reinterpret_cast<const f32x2*>(bm + c);
        const float inv_sqrt_m = 0.08838834764831845f;  // 1/sqrt(128)
        float* __restrict__ gm = (m == 0) ? gq : (m == 1) ? gk : (m == 2) ? gv : go;

        #pragma unroll
        for (int p = 0; p < kGP; ++p) {
            f32x2 v = acc[p] + *reinterpret_cast<const f32x2*>(&sacc[m][p][c]) + b2;
            if (m == 1) { v.x *= inv_sqrt_m; v.y *= inv_sqrt_m; }
            if (m == 3) {
                v.x = 1.f / (1.f + expf(-v.x));
                v.y = 1.f / (1.f + expf(-v.y));
            }
            *reinterpret_cast<f32x2*>(gm + (size_t)(pair_base + p) * kM + c) = v;
            if (m == 0) *reinterpret_cast<f32x2*>(&sq[p][c]) = v;
            if (m == 1) *reinterpret_cast<f32x2*>(&sk[p][c]) = v;
        }
    }

    // ---------------- i/f gates: wave w handles pair w ----------------------
    {
        const int p = w;                  // pair 0..7
        float ip = 0.f, fp = 0.f;
        #pragma unroll
        for (int dd = 0; dd < kD / 64; ++dd) {
            const int d = l + 64 * dd;
            const float xv = xblk[p * kD + d];
            ip += xv * wi[d];
            fp += xv * wf[d];
        }
        #pragma unroll
        for (int msk = 32; msk >= 1; msk >>= 1) {
            ip += __shfl_xor(ip, msk, 64);
            fp += __shfl_xor(fp, msk, 64);
        }
        if (l == 0) {
            sif[p][0] = expf(ip + bi[0]);
            sif[p][1] = 1.f / (1.f + expf(-(fp + bf[0])));
        }
    }
    __syncthreads();

    // ---------------- n update + normalizer ---------------------------------
    if (tid < 32 * kGP) {
        const int p = tid >> 5;         // pair 0..7 (32 threads per pair)
        const int s = tid & 31;
        const size_t pi = (size_t)(pair_base + p);
        const float iv = sif[p][0];
        const float fv = sif[p][1];

        const float4 np4 = *reinterpret_cast<const float4*>(n_prev + pi * kM + 4 * s);
        const float4 k4  = *reinterpret_cast<const float4*>(&sk[p][4 * s]);
        const float4 q4  = *reinterpret_cast<const float4*>(&sq[p][4 * s]);

        float4 n4;
        n4.x = fv * np4.x + iv * k4.x;
        n4.y = fv * np4.y + iv * k4.y;
        n4.z = fv * np4.z + iv * k4.z;
        n4.w = fv * np4.w + iv * k4.w;
        *reinterpret_cast<float4*>(out_n + pi * kM + 4 * s) = n4;

        float nq = n4.x * q4.x + n4.y * q4.y + n4.z * q4.z + n4.w * q4.w;
        nq += __shfl_xor(nq, 16, 64);
        nq += __shfl_xor(nq, 8, 64);
        nq += __shfl_xor(nq, 4, 64);
        nq += __shfl_xor(nq, 2, 64);
        nq += __shfl_xor(nq, 1, 64);
        if (s == 0) {
            gi[pi]   = iv;
            gf[pi]   = fv;
            ginv[pi] = 1.f / fmaxf(fabsf(nq), 1.0f);
        }
    }
}

// ---------------------------------------------------------------------------
// Kernel B: C stream. One block per 64-row half of a pair -> 8192 blocks.
// Phase order: load batch -> compute ALL in place -> store batch at end.
// No vmem consumer follows the NT stores, so the compiler's vmcnt waits for
// loads never serialize behind slow NT-store completion; the store drain
// overlaps the next block. Plain loads (L3 retains C_prev), NT stores.
// ---------------------------------------------------------------------------
__global__ __launch_bounds__(kThreads)
void mlstm_stream(const float* __restrict__ C_prev,
                  const float* __restrict__ gq, const float* __restrict__ gk,
                  const float* __restrict__ gv, const float* __restrict__ go,
                  const float* __restrict__ gi, const float* __restrict__ gf,
                  const float* __restrict__ ginv,
                  float* __restrict__ out_C,
                  float* __restrict__ out_ht)
{
    const int pair = blockIdx.x >> 1;
    const int rblk = (blockIdx.x & 1) * kRB;    // row offset: 0 or 64
    const int tid  = threadIdx.x;
    const int r0   = tid >> 5;      // 0..7
    const int s    = tid & 31;      // col group (cols 4s..4s+3)

    __shared__ float sv_s[kRB];
    __shared__ float sh_s[kRB];

    if (tid < kRB / 4)
        reinterpret_cast<float4*>(sv_s)[tid] =
            reinterpret_cast<const float4*>(gv + (size_t)pair * kM + rblk)[tid];

    const float iv = gi[pair];
    const float fv = gf[pair];
    const float4 k4 = *reinterpret_cast<const float4*>(gk + (size_t)pair * kM + 4 * s);
    const float4 q4 = *reinterpret_cast<const float4*>(gq + (size_t)pair * kM + 4 * s);
    __syncthreads();

    const size_t cbase = (size_t)pair * (kM * kM) + (size_t)rblk * kM;
    const f32x4* cp = reinterpret_cast<const f32x4*>(C_prev + cbase);
    f32x4*       cn = reinterpret_cast<f32x4*>(out_C + cbase);

    // phase 1: 8 independent loads in flight
    f32x4 c4[8];
    #pragma unroll
    for (int j = 0; j < 8; ++j)
        c4[j] = cp[tid + kThreads * j];

    // phase 2: compute in place (C_new overwrites c4), h partials
    float hpart[8];
    #pragma unroll
    for (int j = 0; j < 8; ++j) {
        const int r = r0 + 8 * j;            // row within this 64-row slab
        const float ivr = iv * sv_s[r];
        c4[j].x = fv * c4[j].x + ivr * k4.x;
        c4[j].y = fv * c4[j].y + ivr * k4.y;
        c4[j].z = fv * c4[j].z + ivr * k4.z;
        c4[j].w = fv * c4[j].w + ivr * k4.w;
        hpart[j] = c4[j].x * q4.x + c4[j].y * q4.y
                 + c4[j].z * q4.z + c4[j].w * q4.w;
    }

    // phase 3: store batch (nothing after this waits on vmcnt)
    #pragma unroll
    for (int j = 0; j < 8; ++j)
        __builtin_nontemporal_store(c4[j], &cn[tid + kThreads * j]);

    // h reduction (DS pipe only — independent of the store drain)
    #pragma unroll
    for (int j = 0; j < 8; ++j) {
        float v = hpart[j];
        v += __shfl_xor(v, 16, 64);
        v += __shfl_xor(v, 8, 64);
        v += __shfl_xor(v, 4, 64);
        v += __shfl_xor(v, 2, 64);
        v += __shfl_xor(v, 1, 64);
        if (s == 0) sh_s[r0 + 8 * j] = v;
    }
    __syncthreads();

    if (tid < kRB / 4) {
        const float inv = ginv[pair];
        const float4 h4 = reinterpret_cast<const float4*>(sh_s)[tid];
        const float4 o4 = reinterpret_cast<const float4*>(go + (size_t)pair * kM + rblk)[tid];
        float4 ht4;
        ht4.x = o4.x * h4.x * inv;
        ht4.y = o4.y * h4.y * inv;
        ht4.z = o4.z * h4.z * inv;
        ht4.w = o4.w * h4.w * inv;
        reinterpret_cast<float4*>(out_ht + (size_t)pair * kM + rblk)[tid] = ht4;
    }
}

extern "C" void kernel_launch(void* const* d_in, const int* in_sizes, int n_in,
                              void* d_out, int out_size, void* d_ws, size_t ws_size,
                              hipStream_t stream) {
    const float* x      = (const float*)d_in[0];
    const float* C_prev = (const float*)d_in[1];
    const float* n_prev = (const float*)d_in[2];
    const float* Wq = (const float*)d_in[3];
    const float* bq = (const float*)d_in[4];
    const float* Wk = (const float*)d_in[5];
    const float* bk = (const float*)d_in[6];
    const float* Wv = (const float*)d_in[7];
    const float* bv = (const float*)d_in[8];
    const float* wi = (const float*)d_in[9];
    const float* bi = (const float*)d_in[10];
    const float* wf = (const float*)d_in[11];
    const float* bf = (const float*)d_in[12];
    const float* Wo = (const float*)d_in[13];
    const float* bo = (const float*)d_in[14];

    float* out    = (float*)d_out;
    float* out_ht = out;                                    // (T,B,M)
    float* out_C  = out + (size_t)kNPairs * kM;             // (T,B,M,M)
    float* out_n  = out_C + (size_t)kNPairs * kM * kM;      // (T,B,M)

    // workspace layout (floats)
    float* ws = (float*)d_ws;
    const size_t gsz = (size_t)kNPairs * kM;                // 524288
    float* gq   = ws;
    float* gk   = gq + gsz;
    float* gv   = gk + gsz;
    float* go   = gv + gsz;
    float* gi   = go + gsz;
    float* gf   = gi + kNPairs;
    float* ginv = gf + kNPairs;

    mlstm_gates<<<dim3(kNPairs / kGP), dim3(kGateThreads), 0, stream>>>(
        x, n_prev, Wq, bq, Wk, bk, Wv, bv, wi, bi, wf, bf, Wo, bo,
        gq, gk, gv, go, gi, gf, ginv, out_n);

    mlstm_stream<<<dim3(kNPairs * (kM / kRB)), dim3(kThreads), 0, stream>>>(
        C_prev, gq, gk, gv, go, gi, gf, ginv, out_C, out_ht);
}

// Round 8
// 169.195 us; speedup vs baseline: 1.1119x; 1.1119x over previous
//
#include <hip/hip_runtime.h>
#include <math.h>

// Problem constants
constexpr int kT = 512;
constexpr int kB = 8;
constexpr int kD = 512;
constexpr int kM = 128;
constexpr int kNPairs = kT * kB;        // 4096 independent (t,b) pairs
constexpr int kGP = 8;                  // pairs per block (gates kernel)
constexpr int kThreads = 256;
constexpr int kRB = 64;                 // rows per stream block (2 blocks/pair)

typedef float f32x4 __attribute__((ext_vector_type(4)));
typedef float f32x2 __attribute__((ext_vector_type(2)));

// ---------------------------------------------------------------------------
// Kernel A: gates. 512 blocks x 256 threads (4 waves), 8 pairs/block.
// Wave w owns matrix {Wq,Wk,Wv,Wo}[w]. Lane l: h=l>>5 row parity, s=l&31
// col group (cols 4s..4s+3). Weight loads are float4 covering 2 rows per
// instruction (256 instrs vs 512), batched 8-deep for MLP (8 KB in flight
// per wave). x[p][d] is wave-uniform -> s_load + v_cndmask select by h.
// Cross-half reduce via __shfl_xor(32). 512 MB weight L2 traffic total.
// ---------------------------------------------------------------------------
__global__ __launch_bounds__(kThreads)
void mlstm_gates(const float* __restrict__ x,
                 const float* __restrict__ n_prev,
                 const float* __restrict__ Wq, const float* __restrict__ bq,
                 const float* __restrict__ Wk, const float* __restrict__ bk,
                 const float* __restrict__ Wv, const float* __restrict__ bv,
                 const float* __restrict__ wi, const float* __restrict__ bi,
                 const float* __restrict__ wf, const float* __restrict__ bf,
                 const float* __restrict__ Wo, const float* __restrict__ bo,
                 float* __restrict__ gq, float* __restrict__ gk,
                 float* __restrict__ gv, float* __restrict__ go,
                 float* __restrict__ gi, float* __restrict__ gf,
                 float* __restrict__ ginv,
                 float* __restrict__ out_n)
{
    __shared__ float sq[kGP][kM];     // q (for n-phase)
    __shared__ float sk[kGP][kM];     // k scaled by 1/sqrt(M)
    __shared__ float sif[kGP][2];     // i, f per pair

    const int tid = threadIdx.x;
    const int w   = tid >> 6;         // wave 0..3  <-> matrix q,k,v,o
    const int l   = tid & 63;         // lane
    const int h   = l >> 5;           // row parity within a 2-row step
    const int s   = l & 31;           // col group: cols 4s..4s+3
    const int pair_base = blockIdx.x * kGP;
    const float* __restrict__ xblk = x + (size_t)pair_base * kD;

    // ---------------- main matvec: 4 matrices in parallel across waves ------
    {
        const float* __restrict__ Wm = (w == 0) ? Wq : (w == 1) ? Wk : (w == 2) ? Wv : Wo;
        const float* __restrict__ bm = (w == 0) ? bq : (w == 1) ? bk : (w == 2) ? bv : bo;

        f32x4 acc[kGP];
        #pragma unroll
        for (int p = 0; p < kGP; ++p) acc[p] = (f32x4){0.f, 0.f, 0.f, 0.f};

        for (int d0 = 0; d0 < kD; d0 += 16) {
            // batch of 8 float4 loads (rows d0+2i+h, cols 4s..4s+3)
            f32x4 wb[8];
            #pragma unroll
            for (int i = 0; i < 8; ++i)
                wb[i] = *reinterpret_cast<const f32x4*>(
                    Wm + (size_t)(d0 + 2 * i + h) * kM + 4 * s);

            #pragma unroll
            for (int i = 0; i < 8; ++i) {
                #pragma unroll
                for (int p = 0; p < kGP; ++p) {
                    const float x0 = xblk[p * kD + d0 + 2 * i];     // s_load
                    const float x1 = xblk[p * kD + d0 + 2 * i + 1]; // s_load
                    const float xv = h ? x1 : x0;                    // v_cndmask
                    const f32x4 xx = {xv, xv, xv, xv};
                    acc[p] += xx * wb[i];                            // pk_fma x2
                }
            }
        }

        // cross-half reduce: lanes l and l+32 hold complementary row sums
        #pragma unroll
        for (int p = 0; p < kGP; ++p) {
            acc[p].x += __shfl_xor(acc[p].x, 32, 64);
            acc[p].y += __shfl_xor(acc[p].y, 32, 64);
            acc[p].z += __shfl_xor(acc[p].z, 32, 64);
            acc[p].w += __shfl_xor(acc[p].w, 32, 64);
        }

        if (h == 0) {
            const f32x4 b4 = *reinterpret_cast<const f32x4*>(bm + 4 * s);
            const float inv_sqrt_m = 0.08838834764831845f;  // 1/sqrt(128)
            float* __restrict__ gm = (w == 0) ? gq : (w == 1) ? gk : (w == 2) ? gv : go;

            #pragma unroll
            for (int p = 0; p < kGP; ++p) {
                f32x4 v = acc[p] + b4;
                if (w == 1) {
                    v.x *= inv_sqrt_m; v.y *= inv_sqrt_m;
                    v.z *= inv_sqrt_m; v.w *= inv_sqrt_m;
                }
                if (w == 3) {
                    v.x = 1.f / (1.f + expf(-v.x));
                    v.y = 1.f / (1.f + expf(-v.y));
                    v.z = 1.f / (1.f + expf(-v.z));
                    v.w = 1.f / (1.f + expf(-v.w));
                }
                *reinterpret_cast<f32x4*>(gm + (size_t)(pair_base + p) * kM + 4 * s) = v;
                if (w == 0) *reinterpret_cast<f32x4*>(&sq[p][4 * s]) = v;
                if (w == 1) *reinterpret_cast<f32x4*>(&sk[p][4 * s]) = v;
            }
        }
    }

    // ---------------- i/f gates: each half-wave handles one pair ------------
    {
        const int p = 2 * w + h;          // pair 0..7
        float ip = 0.f, fp = 0.f;
        #pragma unroll
        for (int dd = 0; dd < kD / 32; ++dd) {
            const int d = s + 32 * dd;
            const float xv = xblk[p * kD + d];
            ip += xv * wi[d];
            fp += xv * wf[d];
        }
        #pragma unroll
        for (int msk = 16; msk >= 1; msk >>= 1) {
            ip += __shfl_xor(ip, msk, 64);
            fp += __shfl_xor(fp, msk, 64);
        }
        if (s == 0) {
            sif[p][0] = expf(ip + bi[0]);
            sif[p][1] = 1.f / (1.f + expf(-(fp + bf[0])));
        }
    }
    __syncthreads();

    // ---------------- n update + normalizer ---------------------------------
    {
        const int p = tid >> 5;         // pair 0..7 (32 threads per pair)
        const int ss = tid & 31;
        const size_t pi = (size_t)(pair_base + p);
        const float iv = sif[p][0];
        const float fv = sif[p][1];

        const float4 np4 = *reinterpret_cast<const float4*>(n_prev + pi * kM + 4 * ss);
        const float4 k4  = *reinterpret_cast<const float4*>(&sk[p][4 * ss]);
        const float4 q4  = *reinterpret_cast<const float4*>(&sq[p][4 * ss]);

        float4 n4;
        n4.x = fv * np4.x + iv * k4.x;
        n4.y = fv * np4.y + iv * k4.y;
        n4.z = fv * np4.z + iv * k4.z;
        n4.w = fv * np4.w + iv * k4.w;
        *reinterpret_cast<float4*>(out_n + pi * kM + 4 * ss) = n4;

        float nq = n4.x * q4.x + n4.y * q4.y + n4.z * q4.z + n4.w * q4.w;
        nq += __shfl_xor(nq, 16, 64);
        nq += __shfl_xor(nq, 8, 64);
        nq += __shfl_xor(nq, 4, 64);
        nq += __shfl_xor(nq, 2, 64);
        nq += __shfl_xor(nq, 1, 64);
        if (ss == 0) {
            gi[pi]   = iv;
            gf[pi]   = fv;
            ginv[pi] = 1.f / fmaxf(fabsf(nq), 1.0f);
        }
    }
}

// ---------------------------------------------------------------------------
// Kernel B: C stream. One block per 64-row half of a pair -> 8192 blocks.
// Phase order: load batch -> compute in place -> store batch at end.
// Plain loads (L3 retains C_prev), NT stores (don't evict C_prev from L3).
// ---------------------------------------------------------------------------
__global__ __launch_bounds__(kThreads)
void mlstm_stream(const float* __restrict__ C_prev,
                  const float* __restrict__ gq, const float* __restrict__ gk,
                  const float* __restrict__ gv, const float* __restrict__ go,
                  const float* __restrict__ gi, const float* __restrict__ gf,
                  const float* __restrict__ ginv,
                  float* __restrict__ out_C,
                  float* __restrict__ out_ht)
{
    const int pair = blockIdx.x >> 1;
    const int rblk = (blockIdx.x & 1) * kRB;    // row offset: 0 or 64
    const int tid  = threadIdx.x;
    const int r0   = tid >> 5;      // 0..7
    const int s    = tid & 31;      // col group (cols 4s..4s+3)

    __shared__ float sv_s[kRB];
    __shared__ float sh_s[kRB];

    if (tid < kRB / 4)
        reinterpret_cast<float4*>(sv_s)[tid] =
            reinterpret_cast<const float4*>(gv + (size_t)pair * kM + rblk)[tid];

    const float iv = gi[pair];
    const float fv = gf[pair];
    const float4 k4 = *reinterpret_cast<const float4*>(gk + (size_t)pair * kM + 4 * s);
    const float4 q4 = *reinterpret_cast<const float4*>(gq + (size_t)pair * kM + 4 * s);
    __syncthreads();

    const size_t cbase = (size_t)pair * (kM * kM) + (size_t)rblk * kM;
    const f32x4* cp = reinterpret_cast<const f32x4*>(C_prev + cbase);
    f32x4*       cn = reinterpret_cast<f32x4*>(out_C + cbase);

    // phase 1: 8 independent loads in flight
    f32x4 c4[8];
    #pragma unroll
    for (int j = 0; j < 8; ++j)
        c4[j] = cp[tid + kThreads * j];

    // phase 2: compute in place (C_new overwrites c4), h partials
    float hpart[8];
    #pragma unroll
    for (int j = 0; j < 8; ++j) {
        const int r = r0 + 8 * j;            // row within this 64-row slab
        const float ivr = iv * sv_s[r];
        c4[j].x = fv * c4[j].x + ivr * k4.x;
        c4[j].y = fv * c4[j].y + ivr * k4.y;
        c4[j].z = fv * c4[j].z + ivr * k4.z;
        c4[j].w = fv * c4[j].w + ivr * k4.w;
        hpart[j] = c4[j].x * q4.x + c4[j].y * q4.y
                 + c4[j].z * q4.z + c4[j].w * q4.w;
    }

    // phase 3: store batch (nothing after this waits on vmcnt)
    #pragma unroll
    for (int j = 0; j < 8; ++j)
        __builtin_nontemporal_store(c4[j], &cn[tid + kThreads * j]);

    // h reduction (DS pipe only — independent of the store drain)
    #pragma unroll
    for (int j = 0; j < 8; ++j) {
        float v = hpart[j];
        v += __shfl_xor(v, 16, 64);
        v += __shfl_xor(v, 8, 64);
        v += __shfl_xor(v, 4, 64);
        v += __shfl_xor(v, 2, 64);
        v += __shfl_xor(v, 1, 64);
        if (s == 0) sh_s[r0 + 8 * j] = v;
    }
    __syncthreads();

    if (tid < kRB / 4) {
        const float inv = ginv[pair];
        const float4 h4 = reinterpret_cast<const float4*>(sh_s)[tid];
        const float4 o4 = reinterpret_cast<const float4*>(go + (size_t)pair * kM + rblk)[tid];
        float4 ht4;
        ht4.x = o4.x * h4.x * inv;
        ht4.y = o4.y * h4.y * inv;
        ht4.z = o4.z * h4.z * inv;
        ht4.w = o4.w * h4.w * inv;
        reinterpret_cast<float4*>(out_ht + (size_t)pair * kM + rblk)[tid] = ht4;
    }
}

extern "C" void kernel_launch(void* const* d_in, const int* in_sizes, int n_in,
                              void* d_out, int out_size, void* d_ws, size_t ws_size,
                              hipStream_t stream) {
    const float* x      = (const float*)d_in[0];
    const float* C_prev = (const float*)d_in[1];
    const float* n_prev = (const float*)d_in[2];
    const float* Wq = (const float*)d_in[3];
    const float* bq = (const float*)d_in[4];
    const float* Wk = (const float*)d_in[5];
    const float* bk = (const float*)d_in[6];
    const float* Wv = (const float*)d_in[7];
    const float* bv = (const float*)d_in[8];
    const float* wi = (const float*)d_in[9];
    const float* bi = (const float*)d_in[10];
    const float* wf = (const float*)d_in[11];
    const float* bf = (const float*)d_in[12];
    const float* Wo = (const float*)d_in[13];
    const float* bo = (const float*)d_in[14];

    float* out    = (float*)d_out;
    float* out_ht = out;                                    // (T,B,M)
    float* out_C  = out + (size_t)kNPairs * kM;             // (T,B,M,M)
    float* out_n  = out_C + (size_t)kNPairs * kM * kM;      // (T,B,M)

    // workspace layout (floats)
    float* ws = (float*)d_ws;
    const size_t gsz = (size_t)kNPairs * kM;                // 524288
    float* gq   = ws;
    float* gk   = gq + gsz;
    float* gv   = gk + gsz;
    float* go   = gv + gsz;
    float* gi   = go + gsz;
    float* gf   = gi + kNPairs;
    float* ginv = gf + kNPairs;

    mlstm_gates<<<dim3(kNPairs / kGP), dim3(kThreads), 0, stream>>>(
        x, n_prev, Wq, bq, Wk, bk, Wv, bv, wi, bi, wf, bf, Wo, bo,
        gq, gk, gv, go, gi, gf, ginv, out_n);

    mlstm_stream<<<dim3(kNPairs * (kM / kRB)), dim3(kThreads), 0, stream>>>(
        C_prev, gq, gk, gv, go, gi, gf, ginv, out_C, out_ht);
}

// Round 9
// 160.219 us; speedup vs baseline: 1.1742x; 1.0560x over previous
//
#include <hip/hip_runtime.h>
#include <math.h>

// Problem constants
constexpr int kT = 512;
constexpr int kB = 8;
constexpr int kD = 512;
constexpr int kM = 128;
constexpr int kNPairs = kT * kB;        // 4096 independent (t,b) pairs
constexpr int kGP = 8;                  // pairs per block (gates kernel)
constexpr int kThreads = 256;
constexpr int kRB = 64;                 // rows per stream block (2 blocks/pair)

typedef float f32x4 __attribute__((ext_vector_type(4)));
typedef float f32x2 __attribute__((ext_vector_type(2)));

// ---------------------------------------------------------------------------
// Kernel A: gates. 512 blocks x 256 threads (4 waves), 8 pairs/block.
// Wave w owns matrix {Wq,Wk,Wv,Wo}[w]; lane l owns columns {2l, 2l+1}.
// Round-6 winning structure + explicit 8-deep weight-load batch: 8 f32x2
// loads issued back-to-back (2 KB in flight per wave), then 64 pk-FMAs.
// x[p][d] is wave-uniform -> scalar s_load (SMEM pipe, free for VALU).
// ---------------------------------------------------------------------------
__global__ __launch_bounds__(kThreads)
void mlstm_gates(const float* __restrict__ x,
                 const float* __restrict__ n_prev,
                 const float* __restrict__ Wq, const float* __restrict__ bq,
                 const float* __restrict__ Wk, const float* __restrict__ bk,
                 const float* __restrict__ Wv, const float* __restrict__ bv,
                 const float* __restrict__ wi, const float* __restrict__ bi,
                 const float* __restrict__ wf, const float* __restrict__ bf,
                 const float* __restrict__ Wo, const float* __restrict__ bo,
                 float* __restrict__ gq, float* __restrict__ gk,
                 float* __restrict__ gv, float* __restrict__ go,
                 float* __restrict__ gi, float* __restrict__ gf,
                 float* __restrict__ ginv,
                 float* __restrict__ out_n)
{
    __shared__ float sq[kGP][kM];     // q (for n-phase)
    __shared__ float sk[kGP][kM];     // k scaled by 1/sqrt(M)
    __shared__ float sif[kGP][2];     // i, f per pair

    const int tid = threadIdx.x;
    const int w   = tid >> 6;         // wave 0..3  <-> matrix q,k,v,o
    const int l   = tid & 63;         // lane
    const int pair_base = blockIdx.x * kGP;
    const float* __restrict__ xblk = x + (size_t)pair_base * kD;

    // ---------------- main matvec: 4 matrices in parallel across waves ------
    {
        const float* __restrict__ Wm = (w == 0) ? Wq : (w == 1) ? Wk : (w == 2) ? Wv : Wo;
        const float* __restrict__ bm = (w == 0) ? bq : (w == 1) ? bk : (w == 2) ? bv : bo;

        f32x2 acc[kGP];
        #pragma unroll
        for (int p = 0; p < kGP; ++p) acc[p] = (f32x2){0.f, 0.f};

        const int c = 2 * l;          // column base for this lane

        for (int d0 = 0; d0 < kD; d0 += 8) {
            // explicit batch: 8 weight loads in flight before any FMA
            f32x2 wb[8];
            #pragma unroll
            for (int i = 0; i < 8; ++i)
                wb[i] = *reinterpret_cast<const f32x2*>(Wm + (size_t)(d0 + i) * kM + c);

            #pragma unroll
            for (int i = 0; i < 8; ++i) {
                #pragma unroll
                for (int p = 0; p < kGP; ++p) {
                    const float xv = xblk[p * kD + d0 + i];  // wave-uniform -> s_load
                    const f32x2 xx = {xv, xv};
                    acc[p] += xx * wb[i];                    // v_pk_fma_f32
                }
            }
        }

        const f32x2 b2 = *reinterpret_cast<const f32x2*>(bm + c);
        const float inv_sqrt_m = 0.08838834764831845f;  // 1/sqrt(128)
        float* __restrict__ gm = (w == 0) ? gq : (w == 1) ? gk : (w == 2) ? gv : go;

        #pragma unroll
        for (int p = 0; p < kGP; ++p) {
            f32x2 v = acc[p] + b2;
            if (w == 1) { v.x *= inv_sqrt_m; v.y *= inv_sqrt_m; }
            if (w == 3) {
                v.x = 1.f / (1.f + expf(-v.x));
                v.y = 1.f / (1.f + expf(-v.y));
            }
            *reinterpret_cast<f32x2*>(gm + (size_t)(pair_base + p) * kM + c) = v;
            if (w == 0) *reinterpret_cast<f32x2*>(&sq[p][c]) = v;
            if (w == 1) *reinterpret_cast<f32x2*>(&sk[p][c]) = v;
        }
    }

    // ---------------- i/f gates: each half-wave handles one pair ------------
    {
        const int p = 2 * w + ((tid & 63) >> 5);   // pair 0..7
        const int s = tid & 31;
        float ip = 0.f, fp = 0.f;
        #pragma unroll
        for (int dd = 0; dd < kD / 32; ++dd) {
            const int d = s + 32 * dd;
            const float xv = xblk[p * kD + d];
            ip += xv * wi[d];
            fp += xv * wf[d];
        }
        #pragma unroll
        for (int msk = 16; msk >= 1; msk >>= 1) {
            ip += __shfl_xor(ip, msk, 64);
            fp += __shfl_xor(fp, msk, 64);
        }
        if (s == 0) {
            sif[p][0] = expf(ip + bi[0]);
            sif[p][1] = 1.f / (1.f + expf(-(fp + bf[0])));
        }
    }
    __syncthreads();

    // ---------------- n update + normalizer ---------------------------------
    {
        const int p = tid >> 5;         // pair 0..7 (32 threads per pair)
        const int s = tid & 31;
        const size_t pi = (size_t)(pair_base + p);
        const float iv = sif[p][0];
        const float fv = sif[p][1];

        const float4 np4 = *reinterpret_cast<const float4*>(n_prev + pi * kM + 4 * s);
        const float4 k4  = *reinterpret_cast<const float4*>(&sk[p][4 * s]);
        const float4 q4  = *reinterpret_cast<const float4*>(&sq[p][4 * s]);

        float4 n4;
        n4.x = fv * np4.x + iv * k4.x;
        n4.y = fv * np4.y + iv * k4.y;
        n4.z = fv * np4.z + iv * k4.z;
        n4.w = fv * np4.w + iv * k4.w;
        *reinterpret_cast<float4*>(out_n + pi * kM + 4 * s) = n4;

        float nq = n4.x * q4.x + n4.y * q4.y + n4.z * q4.z + n4.w * q4.w;
        nq += __shfl_xor(nq, 16, 64);
        nq += __shfl_xor(nq, 8, 64);
        nq += __shfl_xor(nq, 4, 64);
        nq += __shfl_xor(nq, 2, 64);
        nq += __shfl_xor(nq, 1, 64);
        if (s == 0) {
            gi[pi]   = iv;
            gf[pi]   = fv;
            ginv[pi] = 1.f / fmaxf(fabsf(nq), 1.0f);
        }
    }
}

// ---------------------------------------------------------------------------
// Kernel B: C stream. One block per 64-row half of a pair -> 8192 blocks.
// Phase order: load batch -> compute in place -> store batch at end.
// Plain loads (L3 retains ~half of C_prev), NT stores (bypass L3).
// ---------------------------------------------------------------------------
__global__ __launch_bounds__(kThreads)
void mlstm_stream(const float* __restrict__ C_prev,
                  const float* __restrict__ gq, const float* __restrict__ gk,
                  const float* __restrict__ gv, const float* __restrict__ go,
                  const float* __restrict__ gi, const float* __restrict__ gf,
                  const float* __restrict__ ginv,
                  float* __restrict__ out_C,
                  float* __restrict__ out_ht)
{
    const int pair = blockIdx.x >> 1;
    const int rblk = (blockIdx.x & 1) * kRB;    // row offset: 0 or 64
    const int tid  = threadIdx.x;
    const int r0   = tid >> 5;      // 0..7
    const int s    = tid & 31;      // col group (cols 4s..4s+3)

    __shared__ float sv_s[kRB];
    __shared__ float sh_s[kRB];

    if (tid < kRB / 4)
        reinterpret_cast<float4*>(sv_s)[tid] =
            reinterpret_cast<const float4*>(gv + (size_t)pair * kM + rblk)[tid];

    const float iv = gi[pair];
    const float fv = gf[pair];
    const float4 k4 = *reinterpret_cast<const float4*>(gk + (size_t)pair * kM + 4 * s);
    const float4 q4 = *reinterpret_cast<const float4*>(gq + (size_t)pair * kM + 4 * s);
    __syncthreads();

    const size_t cbase = (size_t)pair * (kM * kM) + (size_t)rblk * kM;
    const f32x4* cp = reinterpret_cast<const f32x4*>(C_prev + cbase);
    f32x4*       cn = reinterpret_cast<f32x4*>(out_C + cbase);

    // phase 1: 8 independent loads in flight
    f32x4 c4[8];
    #pragma unroll
    for (int j = 0; j < 8; ++j)
        c4[j] = cp[tid + kThreads * j];

    // phase 2: compute in place (C_new overwrites c4), h partials
    float hpart[8];
    #pragma unroll
    for (int j = 0; j < 8; ++j) {
        const int r = r0 + 8 * j;            // row within this 64-row slab
        const float ivr = iv * sv_s[r];
        c4[j].x = fv * c4[j].x + ivr * k4.x;
        c4[j].y = fv * c4[j].y + ivr * k4.y;
        c4[j].z = fv * c4[j].z + ivr * k4.z;
        c4[j].w = fv * c4[j].w + ivr * k4.w;
        hpart[j] = c4[j].x * q4.x + c4[j].y * q4.y
                 + c4[j].z * q4.z + c4[j].w * q4.w;
    }

    // phase 3: store batch (nothing after this waits on vmcnt)
    #pragma unroll
    for (int j = 0; j < 8; ++j)
        __builtin_nontemporal_store(c4[j], &cn[tid + kThreads * j]);

    // h reduction (DS pipe only — independent of the store drain)
    #pragma unroll
    for (int j = 0; j < 8; ++j) {
        float v = hpart[j];
        v += __shfl_xor(v, 16, 64);
        v += __shfl_xor(v, 8, 64);
        v += __shfl_xor(v, 4, 64);
        v += __shfl_xor(v, 2, 64);
        v += __shfl_xor(v, 1, 64);
        if (s == 0) sh_s[r0 + 8 * j] = v;
    }
    __syncthreads();

    if (tid < kRB / 4) {
        const float inv = ginv[pair];
        const float4 h4 = reinterpret_cast<const float4*>(sh_s)[tid];
        const float4 o4 = reinterpret_cast<const float4*>(go + (size_t)pair * kM + rblk)[tid];
        float4 ht4;
        ht4.x = o4.x * h4.x * inv;
        ht4.y = o4.y * h4.y * inv;
        ht4.z = o4.z * h4.z * inv;
        ht4.w = o4.w * h4.w * inv;
        reinterpret_cast<float4*>(out_ht + (size_t)pair * kM + rblk)[tid] = ht4;
    }
}

extern "C" void kernel_launch(void* const* d_in, const int* in_sizes, int n_in,
                              void* d_out, int out_size, void* d_ws, size_t ws_size,
                              hipStream_t stream) {
    const float* x      = (const float*)d_in[0];
    const float* C_prev = (const float*)d_in[1];
    const float* n_prev = (const float*)d_in[2];
    const float* Wq = (const float*)d_in[3];
    const float* bq = (const float*)d_in[4];
    const float* Wk = (const float*)d_in[5];
    const float* bk = (const float*)d_in[6];
    const float* Wv = (const float*)d_in[7];
    const float* bv = (const float*)d_in[8];
    const float* wi = (const float*)d_in[9];
    const float* bi = (const float*)d_in[10];
    const float* wf = (const float*)d_in[11];
    const float* bf = (const float*)d_in[12];
    const float* Wo = (const float*)d_in[13];
    const float* bo = (const float*)d_in[14];

    float* out    = (float*)d_out;
    float* out_ht = out;                                    // (T,B,M)
    float* out_C  = out + (size_t)kNPairs * kM;             // (T,B,M,M)
    float* out_n  = out_C + (size_t)kNPairs * kM * kM;      // (T,B,M)

    // workspace layout (floats)
    float* ws = (float*)d_ws;
    const size_t gsz = (size_t)kNPairs * kM;                // 524288
    float* gq   = ws;
    float* gk   = gq + gsz;
    float* gv   = gk + gsz;
    float* go   = gv + gsz;
    float* gi   = go + gsz;
    float* gf   = gi + kNPairs;
    float* ginv = gf + kNPairs;

    mlstm_gates<<<dim3(kNPairs / kGP), dim3(kThreads), 0, stream>>>(
        x, n_prev, Wq, bq, Wk, bk, Wv, bv, wi, bi, wf, bf, Wo, bo,
        gq, gk, gv, go, gi, gf, ginv, out_n);

    mlstm_stream<<<dim3(kNPairs * (kM / kRB)), dim3(kThreads), 0, stream>>>(
        C_prev, gq, gk, gv, go, gi, gf, ginv, out_C, out_ht);
}

// Round 10
// 139.355 us; speedup vs baseline: 1.3500x; 1.1497x over previous
//
#include <hip/hip_runtime.h>
#include <math.h>

// Problem constants
constexpr int kT = 512;
constexpr int kB = 8;
constexpr int kD = 512;
constexpr int kM = 128;
constexpr int kNPairs = kT * kB;        // 4096 independent (t,b) pairs
constexpr int kGP = 8;                  // pairs per block (gates kernel)
constexpr int kGateThreads = 512;       // 8 waves: 4 matrices x 2 col-halves
constexpr int kThreads = 256;
constexpr int kRB = 64;                 // rows per stream block (2 blocks/pair)

typedef float f32x4 __attribute__((ext_vector_type(4)));
typedef float f32x2 __attribute__((ext_vector_type(2)));

// ---------------------------------------------------------------------------
// Kernel A: gates. 512 blocks x 512 threads (8 waves), 8 pairs/block.
// Waves (2m, 2m+1) own matrix m; each wave covers 64 of 128 columns
// (lane l -> column ch*64+l, scalar loads/FMA). Same 512 MB weight L2
// traffic as the 4-wave version, but 16 waves/CU for latency hiding and
// NO cross-wave reduction (each wave owns the full d-range of its cols).
// x[p][d] is wave-uniform -> scalar s_load (SMEM pipe).
// ---------------------------------------------------------------------------
__global__ __launch_bounds__(kGateThreads)
void mlstm_gates(const float* __restrict__ x,
                 const float* __restrict__ n_prev,
                 const float* __restrict__ Wq, const float* __restrict__ bq,
                 const float* __restrict__ Wk, const float* __restrict__ bk,
                 const float* __restrict__ Wv, const float* __restrict__ bv,
                 const float* __restrict__ wi, const float* __restrict__ bi,
                 const float* __restrict__ wf, const float* __restrict__ bf,
                 const float* __restrict__ Wo, const float* __restrict__ bo,
                 float* __restrict__ gq, float* __restrict__ gk,
                 float* __restrict__ gv, float* __restrict__ go,
                 float* __restrict__ gi, float* __restrict__ gf,
                 float* __restrict__ ginv,
                 float* __restrict__ out_n)
{
    __shared__ float sq[kGP][kM];     // q (for n-phase)
    __shared__ float sk[kGP][kM];     // k scaled by 1/sqrt(M)
    __shared__ float sif[kGP][2];     // i, f per pair

    const int tid = threadIdx.x;
    const int w   = tid >> 6;         // wave 0..7
    const int m   = w >> 1;           // matrix q,k,v,o
    const int ch  = w & 1;            // column half
    const int l   = tid & 63;         // lane
    const int c   = ch * 64 + l;      // column 0..127
    const int pair_base = blockIdx.x * kGP;
    const float* __restrict__ xblk = x + (size_t)pair_base * kD;

    // ---------------- main matvec: 4 matrices x 2 col-halves ----------------
    {
        const float* __restrict__ Wm = (m == 0) ? Wq : (m == 1) ? Wk : (m == 2) ? Wv : Wo;
        const float* __restrict__ bm = (m == 0) ? bq : (m == 1) ? bk : (m == 2) ? bv : bo;

        float acc[kGP];
        #pragma unroll
        for (int p = 0; p < kGP; ++p) acc[p] = 0.f;

        #pragma unroll 8
        for (int d = 0; d < kD; ++d) {
            const float wv = Wm[(size_t)d * kM + c];    // 256 B/wave, coalesced
            #pragma unroll
            for (int p = 0; p < kGP; ++p) {
                const float xv = xblk[p * kD + d];      // wave-uniform -> s_load
                acc[p] = fmaf(xv, wv, acc[p]);
            }
        }

        const float bc = bm[c];
        const float inv_sqrt_m = 0.08838834764831845f;  // 1/sqrt(128)
        float* __restrict__ gm = (m == 0) ? gq : (m == 1) ? gk : (m == 2) ? gv : go;

        #pragma unroll
        for (int p = 0; p < kGP; ++p) {
            float v = acc[p] + bc;
            if (m == 1) v *= inv_sqrt_m;
            if (m == 3) v = 1.f / (1.f + expf(-v));
            gm[(size_t)(pair_base + p) * kM + c] = v;
            if (m == 0) sq[p][c] = v;
            if (m == 1) sk[p][c] = v;
        }
    }

    // ---------------- i/f gates: wave w handles pair w ----------------------
    {
        const int p = w;                  // pair 0..7
        float ip = 0.f, fp = 0.f;
        #pragma unroll
        for (int dd = 0; dd < kD / 64; ++dd) {
            const int d = l + 64 * dd;
            const float xv = xblk[p * kD + d];
            ip += xv * wi[d];
            fp += xv * wf[d];
        }
        #pragma unroll
        for (int msk = 32; msk >= 1; msk >>= 1) {
            ip += __shfl_xor(ip, msk, 64);
            fp += __shfl_xor(fp, msk, 64);
        }
        if (l == 0) {
            sif[p][0] = expf(ip + bi[0]);
            sif[p][1] = 1.f / (1.f + expf(-(fp + bf[0])));
        }
    }
    __syncthreads();

    // ---------------- n update + normalizer ---------------------------------
    if (tid < 32 * kGP) {
        const int p = tid >> 5;         // pair 0..7 (32 threads per pair)
        const int s = tid & 31;
        const size_t pi = (size_t)(pair_base + p);
        const float iv = sif[p][0];
        const float fv = sif[p][1];

        const float4 np4 = *reinterpret_cast<const float4*>(n_prev + pi * kM + 4 * s);
        const float4 k4  = *reinterpret_cast<const float4*>(&sk[p][4 * s]);
        const float4 q4  = *reinterpret_cast<const float4*>(&sq[p][4 * s]);

        float4 n4;
        n4.x = fv * np4.x + iv * k4.x;
        n4.y = fv * np4.y + iv * k4.y;
        n4.z = fv * np4.z + iv * k4.z;
        n4.w = fv * np4.w + iv * k4.w;
        *reinterpret_cast<float4*>(out_n + pi * kM + 4 * s) = n4;

        float nq = n4.x * q4.x + n4.y * q4.y + n4.z * q4.z + n4.w * q4.w;
        nq += __shfl_xor(nq, 16, 64);
        nq += __shfl_xor(nq, 8, 64);
        nq += __shfl_xor(nq, 4, 64);
        nq += __shfl_xor(nq, 2, 64);
        nq += __shfl_xor(nq, 1, 64);
        if (s == 0) {
            gi[pi]   = iv;
            gf[pi]   = fv;
            ginv[pi] = 1.f / fmaxf(fabsf(nq), 1.0f);
        }
    }
}

// ---------------------------------------------------------------------------
// Kernel B: C stream — EXACT round-6 form (best known: 144.5 us total).
// One block per 64-row half of a pair -> 8192 blocks. Load batch, compute
// with NT store interleaved, block-local h reduction, ht epilogue.
// ---------------------------------------------------------------------------
__global__ __launch_bounds__(kThreads)
void mlstm_stream(const float* __restrict__ C_prev,
                  const float* __restrict__ gq, const float* __restrict__ gk,
                  const float* __restrict__ gv, const float* __restrict__ go,
                  const float* __restrict__ gi, const float* __restrict__ gf,
                  const float* __restrict__ ginv,
                  float* __restrict__ out_C,
                  float* __restrict__ out_ht)
{
    const int pair = blockIdx.x >> 1;
    const int rblk = (blockIdx.x & 1) * kRB;    // row offset: 0 or 64
    const int tid  = threadIdx.x;
    const int r0   = tid >> 5;      // 0..7
    const int s    = tid & 31;      // col group (cols 4s..4s+3)

    __shared__ float sv_s[kRB];
    __shared__ float sh_s[kRB];

    if (tid < kRB / 4)
        reinterpret_cast<float4*>(sv_s)[tid] =
            reinterpret_cast<const float4*>(gv + (size_t)pair * kM + rblk)[tid];

    const float iv = gi[pair];
    const float fv = gf[pair];
    const float4 k4 = *reinterpret_cast<const float4*>(gk + (size_t)pair * kM + 4 * s);
    const float4 q4 = *reinterpret_cast<const float4*>(gq + (size_t)pair * kM + 4 * s);
    __syncthreads();

    const size_t cbase = (size_t)pair * (kM * kM) + (size_t)rblk * kM;
    const f32x4* cp = reinterpret_cast<const f32x4*>(C_prev + cbase);
    f32x4*       cn = reinterpret_cast<f32x4*>(out_C + cbase);

    // 8 independent loads in flight
    f32x4 c4[8];
    #pragma unroll
    for (int j = 0; j < 8; ++j)
        c4[j] = cp[tid + kThreads * j];

    float hpart[8];
    #pragma unroll
    for (int j = 0; j < 8; ++j) {
        const int r = r0 + 8 * j;            // row within this 64-row slab
        const float ivr = iv * sv_s[r];
        f32x4 c_new;
        c_new.x = fv * c4[j].x + ivr * k4.x;
        c_new.y = fv * c4[j].y + ivr * k4.y;
        c_new.z = fv * c4[j].z + ivr * k4.z;
        c_new.w = fv * c4[j].w + ivr * k4.w;
        __builtin_nontemporal_store(c_new, &cn[tid + kThreads * j]);
        hpart[j] = c_new.x * q4.x + c_new.y * q4.y
                 + c_new.z * q4.z + c_new.w * q4.w;
    }

    #pragma unroll
    for (int j = 0; j < 8; ++j) {
        float v = hpart[j];
        v += __shfl_xor(v, 16, 64);
        v += __shfl_xor(v, 8, 64);
        v += __shfl_xor(v, 4, 64);
        v += __shfl_xor(v, 2, 64);
        v += __shfl_xor(v, 1, 64);
        if (s == 0) sh_s[r0 + 8 * j] = v;
    }
    __syncthreads();

    if (tid < kRB / 4) {
        const float inv = ginv[pair];
        const float4 h4 = reinterpret_cast<const float4*>(sh_s)[tid];
        const float4 o4 = reinterpret_cast<const float4*>(go + (size_t)pair * kM + rblk)[tid];
        float4 ht4;
        ht4.x = o4.x * h4.x * inv;
        ht4.y = o4.y * h4.y * inv;
        ht4.z = o4.z * h4.z * inv;
        ht4.w = o4.w * h4.w * inv;
        reinterpret_cast<float4*>(out_ht + (size_t)pair * kM + rblk)[tid] = ht4;
    }
}

extern "C" void kernel_launch(void* const* d_in, const int* in_sizes, int n_in,
                              void* d_out, int out_size, void* d_ws, size_t ws_size,
                              hipStream_t stream) {
    const float* x      = (const float*)d_in[0];
    const float* C_prev = (const float*)d_in[1];
    const float* n_prev = (const float*)d_in[2];
    const float* Wq = (const float*)d_in[3];
    const float* bq = (const float*)d_in[4];
    const float* Wk = (const float*)d_in[5];
    const float* bk = (const float*)d_in[6];
    const float* Wv = (const float*)d_in[7];
    const float* bv = (const float*)d_in[8];
    const float* wi = (const float*)d_in[9];
    const float* bi = (const float*)d_in[10];
    const float* wf = (const float*)d_in[11];
    const float* bf = (const float*)d_in[12];
    const float* Wo = (const float*)d_in[13];
    const float* bo = (const float*)d_in[14];

    float* out    = (float*)d_out;
    float* out_ht = out;                                    // (T,B,M)
    float* out_C  = out + (size_t)kNPairs * kM;             // (T,B,M,M)
    float* out_n  = out_C + (size_t)kNPairs * kM * kM;      // (T,B,M)

    // workspace layout (floats)
    float* ws = (float*)d_ws;
    const size_t gsz = (size_t)kNPairs * kM;                // 524288
    float* gq   = ws;
    float* gk   = gq + gsz;
    float* gv   = gk + gsz;
    float* go   = gv + gsz;
    float* gi   = go + gsz;
    float* gf   = gi + kNPairs;
    float* ginv = gf + kNPairs;

    mlstm_gates<<<dim3(kNPairs / kGP), dim3(kGateThreads), 0, stream>>>(
        x, n_prev, Wq, bq, Wk, bk, Wv, bv, wi, bi, wf, bf, Wo, bo,
        gq, gk, gv, go, gi, gf, ginv, out_n);

    mlstm_stream<<<dim3(kNPairs * (kM / kRB)), dim3(kThreads), 0, stream>>>(
        C_prev, gq, gk, gv, go, gi, gf, ginv, out_C, out_ht);
}